// Round 5
// baseline (3076.436 us; speedup 1.0000x reference)
//
#include <hip/hip_runtime.h>
#include <hip/hip_bf16.h>

#define N_FLOWS 50000
#define N_LINKS 5000
#define LPATH 8
#define PLINK 80
#define DIM 16
#define ITERS 12

typedef __attribute__((ext_vector_type(4))) float f32x4;

// ds_swizzle BitMode: offset = (xor<<10) | (or<<5) | and  (within 32-lane half)
#define SWZ(x, pat) __int_as_float(__builtin_amdgcn_ds_swizzle(__float_as_int(x), (pat)))

__device__ __forceinline__ float sigmoid_(float x) { return 1.f / (1.f + __expf(-x)); }
__device__ __forceinline__ float tanh_(float x) { return 1.f - 2.f / (1.f + __expf(2.f * x)); }
__device__ __forceinline__ float selu_(float x) {
    const float sc = 1.0507009873554805f, al = 1.6732632423543772f;
    return x > 0.f ? sc * x : sc * al * expm1f(x);
}
__device__ __forceinline__ float softplus_(float x) {
    return fmaxf(x, 0.f) + log1pf(__expf(-fabsf(x)));
}
__device__ __forceinline__ float hsum4(f32x4 v) {
    return (v[0] + v[1]) + (v[2] + v[3]);
}

// ---- one-time weight repack (transpose to per-lane-contiguous rows) ------
// Wpk  [j][g][k] = pgru_Wr[k*48+g*16+j]   (768)
// Wa_t [j][k]    = att_W[k*16+j]          (256)
// lWk_t[j][g][k] = lgru_Wk[k*48+g*16+j]   (768)
// lWr_t[j][g][k] = lgru_Wr[k*48+g*16+j]   (768)
// pWk_t[c][k]    = pgru_Wk[k*48+c]        (768)
__global__ __launch_bounds__(256) void k_prep(
    const float* __restrict__ pWr, const float* __restrict__ attW,
    const float* __restrict__ lWk, const float* __restrict__ lWr,
    const float* __restrict__ pWk,
    float* __restrict__ Wpk, float* __restrict__ Wa_t,
    float* __restrict__ lWk_t, float* __restrict__ lWr_t,
    float* __restrict__ pWk_t) {
    int i = blockIdx.x * 256 + threadIdx.x;
    if (i < 768) {
        int j = i / 48, r = i % 48;
        Wpk[i] = pWr[(r % 16) * 48 + (r / 16) * 16 + j];
    } else if (i < 1024) {
        int t = i - 768;
        Wa_t[t] = attW[(t % 16) * 16 + (t / 16)];
    } else if (i < 1792) {
        int t = i - 1024;
        int j = t / 48, r = t % 48;
        lWk_t[t] = lWk[(r % 16) * 48 + (r / 16) * 16 + j];
    } else if (i < 2560) {
        int t = i - 1792;
        int j = t / 48, r = t % 48;
        lWr_t[t] = lWr[(r % 16) * 48 + (r / 16) * 16 + j];
    } else if (i < 3328) {
        int t = i - 2560;
        pWk_t[t] = pWk[(t % 16) * 48 + (t / 16)];
    }
}

// ---- load per link -------------------------------------------------------
__global__ __launch_bounds__(256) void k_load(const int* __restrict__ p2l,
                                              const float* __restrict__ flow_traffic,
                                              const float* __restrict__ link_capacity,
                                              float* __restrict__ load) {
    int wave = (blockIdx.x * 256 + threadIdx.x) >> 6;
    int lane = threadIdx.x & 63;
    if (wave >= N_LINKS) return;
    float s = 0.f;
    for (int p = lane; p < PLINK; p += 64) {
        int flow = p2l[(wave * PLINK + p) * 2];
        s += flow_traffic[flow];
    }
#pragma unroll
    for (int off = 32; off; off >>= 1) s += __shfl_xor(s, off, 64);
    if (lane == 0) load[wave] = s / (link_capacity[wave] * 1e9f);
}

// ---- flow embedding ------------------------------------------------------
__global__ __launch_bounds__(256) void k_flow_init(
    const float* __restrict__ flow_traffic, const float* __restrict__ flow_packets,
    const float* __restrict__ ibg, const float* __restrict__ rate,
    const float* __restrict__ p90, const float* __restrict__ pkt_size,
    const float* __restrict__ bitrate_pb, const float* __restrict__ ipg_mean,
    const float* __restrict__ ipg_var, const float* __restrict__ pkts_pb,
    const int* __restrict__ flow_length, const float* __restrict__ flow_type,
    const float* __restrict__ W1, const float* __restrict__ b1,
    const float* __restrict__ W2, const float* __restrict__ b2,
    float* __restrict__ path_state) {
    int f = blockIdx.x * 256 + threadIdx.x;
    if (f >= N_FLOWS) return;
    float feats[13];
    feats[0] = (flow_traffic[f] - 0.1f) * 2.f;
    feats[1] = (flow_packets[f] - 0.1f) * 2.f;
    feats[2] = (ibg[f] - 0.1f) * 2.f;
    feats[3] = (rate[f] - 0.1f) * 2.f;
    feats[4] = (p90[f] - 0.1f) * 2.f;
    feats[5] = (pkt_size[f] - 0.1f) * 2.f;
    feats[6] = (bitrate_pb[f] - 0.1f) * 2.f;
    feats[7] = (ipg_mean[f] - 0.1f) * 2.f;
    feats[8] = (ipg_var[f] - 0.1f) * 2.f;
    feats[9] = (pkts_pb[f] - 0.1f) * 2.f;
    feats[10] = (float)flow_length[f];
    feats[11] = flow_type[f * 2 + 0];
    feats[12] = flow_type[f * 2 + 1];
    float h1[DIM];
#pragma unroll
    for (int j = 0; j < DIM; ++j) {
        float a = b1[j];
#pragma unroll
        for (int k = 0; k < 13; ++k) a = fmaf(feats[k], W1[k * DIM + j], a);
        h1[j] = selu_(a);
    }
#pragma unroll
    for (int j = 0; j < DIM; ++j) {
        float a = b2[j];
#pragma unroll
        for (int k = 0; k < DIM; ++k) a = fmaf(h1[k], W2[k * DIM + j], a);
        path_state[f * DIM + j] = selu_(a);
    }
}

// ---- link embedding + xform precompute (padded [link][j][4] layout) ------
__global__ __launch_bounds__(256) void k_link_init(
    const float* __restrict__ link_capacity, const float* __restrict__ load,
    const float* __restrict__ max_link_load,
    const float* __restrict__ W1, const float* __restrict__ b1,
    const float* __restrict__ W2, const float* __restrict__ b2,
    const float* __restrict__ pWk, const float* __restrict__ pb,
    float* __restrict__ link_state, float* __restrict__ xform) {
    int l = blockIdx.x * 256 + threadIdx.x;
    if (l >= N_LINKS) return;
    float feats[3];
    feats[0] = (link_capacity[l] - 0.1f) * 2.f;
    feats[1] = load[l];
    feats[2] = load[l] / max_link_load[0];
    float h1[DIM];
#pragma unroll
    for (int j = 0; j < DIM; ++j) {
        float a = b1[j];
#pragma unroll
        for (int k = 0; k < 3; ++k) a = fmaf(feats[k], W1[k * DIM + j], a);
        h1[j] = selu_(a);
    }
    float h2[DIM];
#pragma unroll
    for (int j = 0; j < DIM; ++j) {
        float a = b2[j];
#pragma unroll
        for (int k = 0; k < DIM; ++k) a = fmaf(h1[k], W2[k * DIM + j], a);
        h2[j] = selu_(a);
        link_state[l * DIM + j] = h2[j];
    }
#pragma unroll
    for (int c = 0; c < 3 * DIM; ++c) {
        float a = pb[c];
#pragma unroll
        for (int k = 0; k < DIM; ++k) a = fmaf(h2[k], pWk[k * 48 + c], a);
        xform[l * 64 + (c & 15) * 4 + (c >> 4)] = a;
    }
}

// ---- flow pass: GRU scan + fused per-(flow,pos) attention softmax --------
// 16 lanes per flow. Scalar fmaf matvec (3 independent chains); weights
// loaded packed then unpacked to scalar regs; xform gathered as one float4.
template <bool LAST>
__global__ __launch_bounds__(256, 8) void k_flow_pass(
    const int* __restrict__ l2p, const float* __restrict__ xform,
    float* __restrict__ path_state, float* __restrict__ sv,
    const float* __restrict__ Wpk, const float* __restrict__ b,
    const float* __restrict__ Wa_t, const float* __restrict__ attB,
    const float* __restrict__ link_capacity,
    const float* __restrict__ roW1, const float* __restrict__ rob1,
    const float* __restrict__ roW2, const float* __restrict__ rob2,
    const float* __restrict__ roW3, const float* __restrict__ rob3,
    float* __restrict__ out) {
    __shared__ float hbuf[16][16];
    __shared__ float shist[LAST ? 16 : 1][LPATH + 1][17];
    int tid = threadIdx.x;
    int gi = tid >> 4, j = tid & 15;
    int f = blockIdx.x * 16 + gi;
    float wz[16], wr[16], wh[16], wa[16];
#pragma unroll
    for (int q = 0; q < 4; ++q) {
        f32x4 vz = ((const f32x4*)(Wpk + j * 48))[q];
        f32x4 vr = ((const f32x4*)(Wpk + j * 48 + 16))[q];
        f32x4 vh = ((const f32x4*)(Wpk + j * 48 + 32))[q];
        f32x4 va = ((const f32x4*)(Wa_t + j * 16))[q];
#pragma unroll
        for (int e = 0; e < 4; ++e) {
            wz[q * 4 + e] = vz[e];
            wr[q * 4 + e] = vr[e];
            wh[q * 4 + e] = vh[e];
            wa[q * 4 + e] = va[e];
        }
    }
    float b1z = b[48 + j], b1r = b[64 + j], b1h = b[80 + j], ab = attB[j];
    int links[LPATH];
#pragma unroll
    for (int t = 0; t < LPATH; ++t) links[t] = l2p[f * LPATH + t];
    const f32x4* xf = (const f32x4*)xform;
    float h = path_state[f * DIM + j];
    f32x4 nx = xf[links[0] * 16 + j];
#pragma unroll
    for (int p = 0; p <= LPATH; ++p) {
        hbuf[gi][j] = h;
        float hb[16];
#pragma unroll
        for (int q = 0; q < 4; ++q) {
            f32x4 v = ((const f32x4*)hbuf[gi])[q];
            hb[q * 4 + 0] = v[0]; hb[q * 4 + 1] = v[1];
            hb[q * 4 + 2] = v[2]; hb[q * 4 + 3] = v[3];
        }
        if constexpr (!LAST) {
            float att = ab;
#pragma unroll
            for (int k = 0; k < 16; ++k) att = fmaf(hb[k], wa[k], att);
            att = att > 0.f ? att : 0.01f * att;  // leaky_relu
            float m = att;
            m = fmaxf(m, SWZ(m, 0x041F));
            m = fmaxf(m, SWZ(m, 0x081F));
            m = fmaxf(m, SWZ(m, 0x101F));
            m = fmaxf(m, SWZ(m, 0x201F));
            float e = __expf(att - m);
            float s = e;
            s += SWZ(s, 0x041F);
            s += SWZ(s, 0x081F);
            s += SWZ(s, 0x101F);
            s += SWZ(s, 0x201F);
            sv[p * (N_FLOWS * DIM) + f * DIM + j] = (e / s) * h;
        } else {
            shist[gi][p][j] = h;
        }
        if (p < LPATH) {
            f32x4 cx = nx;
            if (p + 1 < LPATH) nx = xf[links[p + 1] * 16 + j];
            float gz = b1z, gr = b1r, gh = b1h;
#pragma unroll
            for (int k = 0; k < 16; ++k) {
                gz = fmaf(hb[k], wz[k], gz);
                gr = fmaf(hb[k], wr[k], gr);
                gh = fmaf(hb[k], wh[k], gh);
            }
            float z = sigmoid_(cx[0] + gz);
            float r = sigmoid_(cx[1] + gr);
            float cand = tanh_(fmaf(r, gh, cx[2]));
            h = z * h + (1.f - z) * cand;
        }
    }
    if constexpr (!LAST) {
        path_state[f * DIM + j] = h;
    } else {
        __syncthreads();
        if (tid < 128) {  // 16 flows x 8 positions
            int fl = tid >> 3, t = tid & 7;
            int fg = blockIdx.x * 16 + fl;
            const float* s = shist[fl][t + 1];
            float h1[8];
#pragma unroll
            for (int m_ = 0; m_ < 8; ++m_) {
                float a = rob1[m_];
#pragma unroll
                for (int k = 0; k < 16; ++k) a = fmaf(s[k], roW1[k * 8 + m_], a);
                h1[m_] = selu_(a);
            }
            float h2[4];
#pragma unroll
            for (int q = 0; q < 4; ++q) {
                float a = rob2[q];
#pragma unroll
                for (int m_ = 0; m_ < 8; ++m_) a = fmaf(h1[m_], roW2[m_ * 4 + q], a);
                h2[q] = selu_(a);
            }
            float o = rob3[0];
#pragma unroll
            for (int q = 0; q < 4; ++q) o = fmaf(h2[q], roW3[q], o);
            o = softplus_(o);
            int link = l2p[fg * LPATH + t];
            float v = o / link_capacity[link];
            v += SWZ(v, 0x041F);
            v += SWZ(v, 0x081F);
            v += SWZ(v, 0x101F);
            if (t == 0) out[fg] = v;
        }
    }
}

// ---- link pass: gather-sum of sv + link GRU + fused xform ----------------
// 4 links per 256-block, one wave per link (16 j-lanes x 4 p-slices).
__global__ __launch_bounds__(256, 8) void k_link_pass(
    const int* __restrict__ p2l, const float* __restrict__ sv,
    float* __restrict__ link_state,
    const float* __restrict__ lWk_t, const float* __restrict__ lWr_t,
    const float* __restrict__ b,
    const float* __restrict__ pWk_t, const float* __restrict__ pb,
    float* __restrict__ xform) {
    __shared__ float xb_[4][16];
    __shared__ float hb_[4][16];
    int tid = threadIdx.x;
    int li = tid >> 6;
    int lane = tid & 63;
    int sl = lane >> 4, j = lane & 15;
    int link = blockIdx.x * 4 + li;
    float ps = 0.f;
#pragma unroll 4
    for (int i = 0; i < PLINK / 4; ++i) {
        int p = sl + 4 * i;
        int2 fp = ((const int2*)p2l)[link * PLINK + p];
        ps += sv[fp.y * (N_FLOWS * DIM) + fp.x * DIM + j];
    }
    ps += __shfl_xor(ps, 16, 64);
    ps += __shfl_xor(ps, 32, 64);
    float h = link_state[link * DIM + j];
    if (sl == 0) { xb_[li][j] = ps; hb_[li][j] = h; }
    float xv[16], hv[16];
#pragma unroll
    for (int q = 0; q < 4; ++q) {
        f32x4 x4 = ((const f32x4*)xb_[li])[q];
        f32x4 h4 = ((const f32x4*)hb_[li])[q];
#pragma unroll
        for (int e = 0; e < 4; ++e) { xv[q * 4 + e] = x4[e]; hv[q * 4 + e] = h4[e]; }
    }
    float az = b[j], ar = b[16 + j], ah = b[32 + j];
    float gz = b[48 + j], gr = b[64 + j], gh = b[80 + j];
    const float* kz = lWk_t + j * 48;
    const float* rz = lWr_t + j * 48;
#pragma unroll
    for (int k = 0; k < 16; ++k) {
        az = fmaf(xv[k], kz[k], az);
        ar = fmaf(xv[k], kz[16 + k], ar);
        ah = fmaf(xv[k], kz[32 + k], ah);
        gz = fmaf(hv[k], rz[k], gz);
        gr = fmaf(hv[k], rz[16 + k], gr);
        gh = fmaf(hv[k], rz[32 + k], gh);
    }
    float z = sigmoid_(az + gz);
    float r = sigmoid_(ar + gr);
    float hn = z * h + (1.f - z) * tanh_(fmaf(r, gh, ah));
    if (sl == 0) {
        link_state[link * DIM + j] = hn;
        hb_[li][j] = hn;  // re-broadcast new state for xform
    }
    float nv[16];
#pragma unroll
    for (int q = 0; q < 4; ++q) {
        f32x4 n4 = ((const f32x4*)hb_[li])[q];
#pragma unroll
        for (int e = 0; e < 4; ++e) nv[q * 4 + e] = n4[e];
    }
    int c = lane;
    if (c < 48) {
        const float* pw = pWk_t + c * 16;
        float a = pb[c];
#pragma unroll
        for (int k = 0; k < 16; ++k) a = fmaf(nv[k], pw[k], a);
        xform[link * 64 + (c & 15) * 4 + (c >> 4)] = a;
    }
}

extern "C" void kernel_launch(void* const* d_in, const int* in_sizes, int n_in,
                              void* d_out, int out_size, void* d_ws, size_t ws_size,
                              hipStream_t stream) {
    const float* flow_traffic = (const float*)d_in[0];
    const float* flow_packets = (const float*)d_in[1];
    const float* max_link_load = (const float*)d_in[2];
    const float* flow_pkts_per_burst = (const float*)d_in[3];
    const float* flow_bitrate_per_burst = (const float*)d_in[4];
    const float* flow_packet_size = (const float*)d_in[5];
    const float* flow_type = (const float*)d_in[6];
    const float* flow_ipg_mean = (const float*)d_in[7];
    const float* ibg = (const float*)d_in[8];
    const float* flow_p90 = (const float*)d_in[9];
    const float* rate = (const float*)d_in[10];
    const float* flow_ipg_var = (const float*)d_in[11];
    const float* link_capacity = (const float*)d_in[12];
    const float* fe_W1 = (const float*)d_in[13];
    const float* fe_b1 = (const float*)d_in[14];
    const float* fe_W2 = (const float*)d_in[15];
    const float* fe_b2 = (const float*)d_in[16];
    const float* le_W1 = (const float*)d_in[17];
    const float* le_b1 = (const float*)d_in[18];
    const float* le_W2 = (const float*)d_in[19];
    const float* le_b2 = (const float*)d_in[20];
    const float* att_W = (const float*)d_in[21];
    const float* att_b = (const float*)d_in[22];
    const float* pgru_Wk = (const float*)d_in[23];
    const float* pgru_Wr = (const float*)d_in[24];
    const float* pgru_b = (const float*)d_in[25];
    const float* lgru_Wk = (const float*)d_in[26];
    const float* lgru_Wr = (const float*)d_in[27];
    const float* lgru_b = (const float*)d_in[28];
    const float* ro_W1 = (const float*)d_in[29];
    const float* ro_b1 = (const float*)d_in[30];
    const float* ro_W2 = (const float*)d_in[31];
    const float* ro_b2 = (const float*)d_in[32];
    const float* ro_W3 = (const float*)d_in[33];
    const float* ro_b3 = (const float*)d_in[34];
    const int* flow_length = (const int*)d_in[35];
    const int* l2p = (const int*)d_in[36];
    const int* p2l = (const int*)d_in[37];

    float* ws = (float*)d_ws;
    float* path_state = ws;                      // 800000
    float* link_state = ws + 800000;             // 80000
    float* sv = ws + 880000;                     // 7200000  [pos][flow][16]
    float* load = ws + 8080000;                  // 5000
    float* xform = ws + 8085000;                 // 320000   [link][16][4]
    float* Wpk = ws + 8405000;                   // 768
    float* Wa_t = ws + 8405768;                  // 256
    float* lWk_t = ws + 8406024;                 // 768
    float* lWr_t = ws + 8406792;                 // 768
    float* pWk_t = ws + 8407560;                 // 768
    if (ws_size < (size_t)8408328 * 4) return;

    k_prep<<<13, 256, 0, stream>>>(pgru_Wr, att_W, lgru_Wk, lgru_Wr, pgru_Wk,
                                   Wpk, Wa_t, lWk_t, lWr_t, pWk_t);
    k_load<<<(N_LINKS * 64 + 255) / 256, 256, 0, stream>>>(p2l, flow_traffic,
                                                           link_capacity, load);
    k_flow_init<<<(N_FLOWS + 255) / 256, 256, 0, stream>>>(
        flow_traffic, flow_packets, ibg, rate, flow_p90, flow_packet_size,
        flow_bitrate_per_burst, flow_ipg_mean, flow_ipg_var, flow_pkts_per_burst,
        flow_length, flow_type, fe_W1, fe_b1, fe_W2, fe_b2, path_state);
    k_link_init<<<(N_LINKS + 255) / 256, 256, 0, stream>>>(
        link_capacity, load, max_link_load, le_W1, le_b1, le_W2, le_b2,
        pgru_Wk, pgru_b, link_state, xform);

    for (int it = 0; it < ITERS - 1; ++it) {
        k_flow_pass<false><<<N_FLOWS / 16, 256, 0, stream>>>(
            l2p, xform, path_state, sv, Wpk, pgru_b, Wa_t, att_b,
            nullptr, nullptr, nullptr, nullptr, nullptr, nullptr, nullptr,
            nullptr);
        k_link_pass<<<N_LINKS / 4, 256, 0, stream>>>(
            p2l, sv, link_state, lWk_t, lWr_t, lgru_b, pWk_t, pgru_b, xform);
    }
    // final iteration: no sv / no link update needed; fuse readout.
    k_flow_pass<true><<<N_FLOWS / 16, 256, 0, stream>>>(
        l2p, xform, path_state, sv, Wpk, pgru_b, Wa_t, att_b,
        link_capacity, ro_W1, ro_b1, ro_W2, ro_b2, ro_W3, ro_b3,
        (float*)d_out);
}

// Round 6
// 656.335 us; speedup vs baseline: 4.6873x; 4.6873x over previous
//
#include <hip/hip_runtime.h>
#include <hip/hip_bf16.h>

#define N_FLOWS 50000
#define N_LINKS 5000
#define LPATH 8
#define PLINK 80
#define DIM 16
#define ITERS 12

typedef __attribute__((ext_vector_type(4))) float f32x4;

// ds_swizzle BitMode: offset = (xor<<10) | (or<<5) | and  (within 32-lane half)
#define SWZ(x, pat) __int_as_float(__builtin_amdgcn_ds_swizzle(__float_as_int(x), (pat)))

__device__ __forceinline__ float sigmoid_(float x) { return 1.f / (1.f + __expf(-x)); }
__device__ __forceinline__ float tanh_(float x) { return 1.f - 2.f / (1.f + __expf(2.f * x)); }
__device__ __forceinline__ float selu_(float x) {
    const float sc = 1.0507009873554805f, al = 1.6732632423543772f;
    return x > 0.f ? sc * x : sc * al * expm1f(x);
}
__device__ __forceinline__ float softplus_(float x) {
    return fmaxf(x, 0.f) + log1pf(__expf(-fabsf(x)));
}

// ---- one-time weight repack (transpose to per-lane-contiguous rows) ------
__global__ __launch_bounds__(256) void k_prep(
    const float* __restrict__ pWr, const float* __restrict__ attW,
    const float* __restrict__ lWk, const float* __restrict__ lWr,
    const float* __restrict__ pWk,
    float* __restrict__ Wpk, float* __restrict__ Wa_t,
    float* __restrict__ lWk_t, float* __restrict__ lWr_t,
    float* __restrict__ pWk_t) {
    int i = blockIdx.x * 256 + threadIdx.x;
    if (i < 768) {
        int j = i / 48, r = i % 48;
        Wpk[i] = pWr[(r % 16) * 48 + (r / 16) * 16 + j];
    } else if (i < 1024) {
        int t = i - 768;
        Wa_t[t] = attW[(t % 16) * 16 + (t / 16)];
    } else if (i < 1792) {
        int t = i - 1024;
        int j = t / 48, r = t % 48;
        lWk_t[t] = lWk[(r % 16) * 48 + (r / 16) * 16 + j];
    } else if (i < 2560) {
        int t = i - 1792;
        int j = t / 48, r = t % 48;
        lWr_t[t] = lWr[(r % 16) * 48 + (r / 16) * 16 + j];
    } else if (i < 3328) {
        int t = i - 2560;
        pWk_t[t] = pWk[(t % 16) * 48 + (t / 16)];
    }
}

// ---- load per link -------------------------------------------------------
__global__ __launch_bounds__(256) void k_load(const int* __restrict__ p2l,
                                              const float* __restrict__ flow_traffic,
                                              const float* __restrict__ link_capacity,
                                              float* __restrict__ load) {
    int wave = (blockIdx.x * 256 + threadIdx.x) >> 6;
    int lane = threadIdx.x & 63;
    if (wave >= N_LINKS) return;
    float s = 0.f;
    for (int p = lane; p < PLINK; p += 64) {
        int flow = p2l[(wave * PLINK + p) * 2];
        s += flow_traffic[flow];
    }
#pragma unroll
    for (int off = 32; off; off >>= 1) s += __shfl_xor(s, off, 64);
    if (lane == 0) load[wave] = s / (link_capacity[wave] * 1e9f);
}

// ---- flow embedding ------------------------------------------------------
__global__ __launch_bounds__(256) void k_flow_init(
    const float* __restrict__ flow_traffic, const float* __restrict__ flow_packets,
    const float* __restrict__ ibg, const float* __restrict__ rate,
    const float* __restrict__ p90, const float* __restrict__ pkt_size,
    const float* __restrict__ bitrate_pb, const float* __restrict__ ipg_mean,
    const float* __restrict__ ipg_var, const float* __restrict__ pkts_pb,
    const int* __restrict__ flow_length, const float* __restrict__ flow_type,
    const float* __restrict__ W1, const float* __restrict__ b1,
    const float* __restrict__ W2, const float* __restrict__ b2,
    float* __restrict__ path_state) {
    int f = blockIdx.x * 256 + threadIdx.x;
    if (f >= N_FLOWS) return;
    float feats[13];
    feats[0] = (flow_traffic[f] - 0.1f) * 2.f;
    feats[1] = (flow_packets[f] - 0.1f) * 2.f;
    feats[2] = (ibg[f] - 0.1f) * 2.f;
    feats[3] = (rate[f] - 0.1f) * 2.f;
    feats[4] = (p90[f] - 0.1f) * 2.f;
    feats[5] = (pkt_size[f] - 0.1f) * 2.f;
    feats[6] = (bitrate_pb[f] - 0.1f) * 2.f;
    feats[7] = (ipg_mean[f] - 0.1f) * 2.f;
    feats[8] = (ipg_var[f] - 0.1f) * 2.f;
    feats[9] = (pkts_pb[f] - 0.1f) * 2.f;
    feats[10] = (float)flow_length[f];
    feats[11] = flow_type[f * 2 + 0];
    feats[12] = flow_type[f * 2 + 1];
    float h1[DIM];
#pragma unroll
    for (int j = 0; j < DIM; ++j) {
        float a = b1[j];
#pragma unroll
        for (int k = 0; k < 13; ++k) a = fmaf(feats[k], W1[k * DIM + j], a);
        h1[j] = selu_(a);
    }
#pragma unroll
    for (int j = 0; j < DIM; ++j) {
        float a = b2[j];
#pragma unroll
        for (int k = 0; k < DIM; ++k) a = fmaf(h1[k], W2[k * DIM + j], a);
        path_state[f * DIM + j] = selu_(a);
    }
}

// ---- link embedding + xform precompute (padded [link][j][4] layout) ------
__global__ __launch_bounds__(256) void k_link_init(
    const float* __restrict__ link_capacity, const float* __restrict__ load,
    const float* __restrict__ max_link_load,
    const float* __restrict__ W1, const float* __restrict__ b1,
    const float* __restrict__ W2, const float* __restrict__ b2,
    const float* __restrict__ pWk, const float* __restrict__ pb,
    float* __restrict__ link_state, float* __restrict__ xform) {
    int l = blockIdx.x * 256 + threadIdx.x;
    if (l >= N_LINKS) return;
    float feats[3];
    feats[0] = (link_capacity[l] - 0.1f) * 2.f;
    feats[1] = load[l];
    feats[2] = load[l] / max_link_load[0];
    float h1[DIM];
#pragma unroll
    for (int j = 0; j < DIM; ++j) {
        float a = b1[j];
#pragma unroll
        for (int k = 0; k < 3; ++k) a = fmaf(feats[k], W1[k * DIM + j], a);
        h1[j] = selu_(a);
    }
    float h2[DIM];
#pragma unroll
    for (int j = 0; j < DIM; ++j) {
        float a = b2[j];
#pragma unroll
        for (int k = 0; k < DIM; ++k) a = fmaf(h1[k], W2[k * DIM + j], a);
        h2[j] = selu_(a);
        link_state[l * DIM + j] = h2[j];
    }
#pragma unroll
    for (int c = 0; c < 3 * DIM; ++c) {
        float a = pb[c];
#pragma unroll
        for (int k = 0; k < DIM; ++k) a = fmaf(h2[k], pWk[k * 48 + c], a);
        xform[l * 64 + (c & 15) * 4 + (c >> 4)] = a;
    }
}

// ---- flow pass: 2 flows per 16-lane group (2 independent GRU chains) -----
// Lane j of group gi handles hidden dim j of flows base+gi and base+16+gi.
template <bool LAST>
__global__ __launch_bounds__(256) void k_flow_pass(
    const int* __restrict__ l2p, const float* __restrict__ xform,
    float* __restrict__ path_state, float* __restrict__ sv,
    const float* __restrict__ Wpk, const float* __restrict__ b,
    const float* __restrict__ Wa_t, const float* __restrict__ attB,
    const float* __restrict__ link_capacity,
    const float* __restrict__ roW1, const float* __restrict__ rob1,
    const float* __restrict__ roW2, const float* __restrict__ rob2,
    const float* __restrict__ roW3, const float* __restrict__ rob3,
    float* __restrict__ out) {
    __shared__ float hbuf[2][16][16];
    __shared__ float shist[LAST ? 32 : 1][LPATH + 1][17];
    int tid = threadIdx.x;
    int gi = tid >> 4, j = tid & 15;
    int base = blockIdx.x * 32;
    int fA = base + gi;
    int fB = base + 16 + gi;
    int fAc = fA < N_FLOWS ? fA : N_FLOWS - 1;
    int fBc = fB < N_FLOWS ? fB : N_FLOWS - 1;
    float wz[16], wr[16], wh[16], wa[16];
#pragma unroll
    for (int q = 0; q < 4; ++q) {
        f32x4 vz = ((const f32x4*)(Wpk + j * 48))[q];
        f32x4 vr = ((const f32x4*)(Wpk + j * 48 + 16))[q];
        f32x4 vh = ((const f32x4*)(Wpk + j * 48 + 32))[q];
        f32x4 va = ((const f32x4*)(Wa_t + j * 16))[q];
#pragma unroll
        for (int e = 0; e < 4; ++e) {
            wz[q * 4 + e] = vz[e];
            wr[q * 4 + e] = vr[e];
            wh[q * 4 + e] = vh[e];
            wa[q * 4 + e] = va[e];
        }
    }
    float b1z = b[48 + j], b1r = b[64 + j], b1h = b[80 + j], ab = attB[j];
    int linksA[LPATH], linksB[LPATH];
    {
        int4 a0 = ((const int4*)(l2p + fAc * LPATH))[0];
        int4 a1 = ((const int4*)(l2p + fAc * LPATH))[1];
        int4 c0 = ((const int4*)(l2p + fBc * LPATH))[0];
        int4 c1 = ((const int4*)(l2p + fBc * LPATH))[1];
        linksA[0] = a0.x; linksA[1] = a0.y; linksA[2] = a0.z; linksA[3] = a0.w;
        linksA[4] = a1.x; linksA[5] = a1.y; linksA[6] = a1.z; linksA[7] = a1.w;
        linksB[0] = c0.x; linksB[1] = c0.y; linksB[2] = c0.z; linksB[3] = c0.w;
        linksB[4] = c1.x; linksB[5] = c1.y; linksB[6] = c1.z; linksB[7] = c1.w;
    }
    const f32x4* xf = (const f32x4*)xform;
    float hA = path_state[fAc * DIM + j];
    float hB = path_state[fBc * DIM + j];
    f32x4 nxA = xf[linksA[0] * 16 + j];
    f32x4 nxB = xf[linksB[0] * 16 + j];
#pragma unroll
    for (int p = 0; p <= LPATH; ++p) {
        hbuf[0][gi][j] = hA;
        hbuf[1][gi][j] = hB;
        float ha[16], hb[16];
#pragma unroll
        for (int q = 0; q < 4; ++q) {
            f32x4 vA = ((const f32x4*)hbuf[0][gi])[q];
            f32x4 vB = ((const f32x4*)hbuf[1][gi])[q];
#pragma unroll
            for (int e = 0; e < 4; ++e) {
                ha[q * 4 + e] = vA[e];
                hb[q * 4 + e] = vB[e];
            }
        }
        if constexpr (!LAST) {
            float attA = ab, attB_ = ab;
#pragma unroll
            for (int k = 0; k < 16; ++k) {
                attA = fmaf(ha[k], wa[k], attA);
                attB_ = fmaf(hb[k], wa[k], attB_);
            }
            attA = attA > 0.f ? attA : 0.01f * attA;
            attB_ = attB_ > 0.f ? attB_ : 0.01f * attB_;
            float mA = attA, mB = attB_;
            mA = fmaxf(mA, SWZ(mA, 0x041F)); mB = fmaxf(mB, SWZ(mB, 0x041F));
            mA = fmaxf(mA, SWZ(mA, 0x081F)); mB = fmaxf(mB, SWZ(mB, 0x081F));
            mA = fmaxf(mA, SWZ(mA, 0x101F)); mB = fmaxf(mB, SWZ(mB, 0x101F));
            mA = fmaxf(mA, SWZ(mA, 0x201F)); mB = fmaxf(mB, SWZ(mB, 0x201F));
            float eA = __expf(attA - mA), eB = __expf(attB_ - mB);
            float sA = eA, sB = eB;
            sA += SWZ(sA, 0x041F); sB += SWZ(sB, 0x041F);
            sA += SWZ(sA, 0x081F); sB += SWZ(sB, 0x081F);
            sA += SWZ(sA, 0x101F); sB += SWZ(sB, 0x101F);
            sA += SWZ(sA, 0x201F); sB += SWZ(sB, 0x201F);
            sv[p * (N_FLOWS * DIM) + fA * DIM + j] = (eA / sA) * hA;
            if (fB < N_FLOWS)
                sv[p * (N_FLOWS * DIM) + fB * DIM + j] = (eB / sB) * hB;
        } else {
            shist[gi][p][j] = hA;
            shist[gi + 16][p][j] = hB;
        }
        if (p < LPATH) {
            f32x4 cxA = nxA, cxB = nxB;
            if (p + 1 < LPATH) {
                nxA = xf[linksA[p + 1] * 16 + j];
                nxB = xf[linksB[p + 1] * 16 + j];
            }
            float gzA = b1z, grA = b1r, ghA = b1h;
            float gzB = b1z, grB = b1r, ghB = b1h;
#pragma unroll
            for (int k = 0; k < 16; ++k) {
                gzA = fmaf(ha[k], wz[k], gzA);
                grA = fmaf(ha[k], wr[k], grA);
                ghA = fmaf(ha[k], wh[k], ghA);
                gzB = fmaf(hb[k], wz[k], gzB);
                grB = fmaf(hb[k], wr[k], grB);
                ghB = fmaf(hb[k], wh[k], ghB);
            }
            float zA = sigmoid_(cxA[0] + gzA);
            float rA = sigmoid_(cxA[1] + grA);
            float cA = tanh_(fmaf(rA, ghA, cxA[2]));
            hA = zA * hA + (1.f - zA) * cA;
            float zB = sigmoid_(cxB[0] + gzB);
            float rB = sigmoid_(cxB[1] + grB);
            float cB = tanh_(fmaf(rB, ghB, cxB[2]));
            hB = zB * hB + (1.f - zB) * cB;
        }
    }
    if constexpr (!LAST) {
        path_state[fA * DIM + j] = hA;
        if (fB < N_FLOWS) path_state[fB * DIM + j] = hB;
    } else {
        __syncthreads();
        {  // 32 flows x 8 positions = 256 threads
            int fl = tid >> 3, t = tid & 7;
            int fg = base + fl;
            const float* s = shist[fl][t + 1];
            float h1[8];
#pragma unroll
            for (int m_ = 0; m_ < 8; ++m_) {
                float a = rob1[m_];
#pragma unroll
                for (int k = 0; k < 16; ++k) a = fmaf(s[k], roW1[k * 8 + m_], a);
                h1[m_] = selu_(a);
            }
            float h2[4];
#pragma unroll
            for (int q = 0; q < 4; ++q) {
                float a = rob2[q];
#pragma unroll
                for (int m_ = 0; m_ < 8; ++m_) a = fmaf(h1[m_], roW2[m_ * 4 + q], a);
                h2[q] = selu_(a);
            }
            float o = rob3[0];
#pragma unroll
            for (int q = 0; q < 4; ++q) o = fmaf(h2[q], roW3[q], o);
            o = softplus_(o);
            int fgc = fg < N_FLOWS ? fg : N_FLOWS - 1;
            int link = l2p[fgc * LPATH + t];
            float v = o / link_capacity[link];
            v += SWZ(v, 0x041F);
            v += SWZ(v, 0x081F);
            v += SWZ(v, 0x101F);
            if (t == 0 && fg < N_FLOWS) out[fg] = v;
        }
    }
}

// ---- link pass: gather-sum of sv + link GRU + fused xform ----------------
// 4 links per 256-block, one wave per link (16 j-lanes x 4 p-slices).
__global__ __launch_bounds__(256, 4) void k_link_pass(
    const int* __restrict__ p2l, const float* __restrict__ sv,
    float* __restrict__ link_state,
    const float* __restrict__ lWk_t, const float* __restrict__ lWr_t,
    const float* __restrict__ b,
    const float* __restrict__ pWk_t, const float* __restrict__ pb,
    float* __restrict__ xform) {
    __shared__ float xb_[4][16];
    __shared__ float hb_[4][16];
    int tid = threadIdx.x;
    int li = tid >> 6;
    int lane = tid & 63;
    int sl = lane >> 4, j = lane & 15;
    int link = blockIdx.x * 4 + li;
    float ps = 0.f;
#pragma unroll 4
    for (int i = 0; i < PLINK / 4; ++i) {
        int p = sl + 4 * i;
        int2 fp = ((const int2*)p2l)[link * PLINK + p];
        ps += sv[fp.y * (N_FLOWS * DIM) + fp.x * DIM + j];
    }
    ps += __shfl_xor(ps, 16, 64);
    ps += __shfl_xor(ps, 32, 64);
    float h = link_state[link * DIM + j];
    if (sl == 0) { xb_[li][j] = ps; hb_[li][j] = h; }
    float xv[16], hv[16];
#pragma unroll
    for (int q = 0; q < 4; ++q) {
        f32x4 x4 = ((const f32x4*)xb_[li])[q];
        f32x4 h4 = ((const f32x4*)hb_[li])[q];
#pragma unroll
        for (int e = 0; e < 4; ++e) { xv[q * 4 + e] = x4[e]; hv[q * 4 + e] = h4[e]; }
    }
    float az = b[j], ar = b[16 + j], ah = b[32 + j];
    float gz = b[48 + j], gr = b[64 + j], gh = b[80 + j];
    const float* kz = lWk_t + j * 48;
    const float* rz = lWr_t + j * 48;
#pragma unroll
    for (int k = 0; k < 16; ++k) {
        az = fmaf(xv[k], kz[k], az);
        ar = fmaf(xv[k], kz[16 + k], ar);
        ah = fmaf(xv[k], kz[32 + k], ah);
        gz = fmaf(hv[k], rz[k], gz);
        gr = fmaf(hv[k], rz[16 + k], gr);
        gh = fmaf(hv[k], rz[32 + k], gh);
    }
    float z = sigmoid_(az + gz);
    float r = sigmoid_(ar + gr);
    float hn = z * h + (1.f - z) * tanh_(fmaf(r, gh, ah));
    if (sl == 0) {
        link_state[link * DIM + j] = hn;
        hb_[li][j] = hn;  // re-broadcast new state for xform
    }
    float nv[16];
#pragma unroll
    for (int q = 0; q < 4; ++q) {
        f32x4 n4 = ((const f32x4*)hb_[li])[q];
#pragma unroll
        for (int e = 0; e < 4; ++e) nv[q * 4 + e] = n4[e];
    }
    int c = lane;
    if (c < 48) {
        const float* pw = pWk_t + c * 16;
        float a = pb[c];
#pragma unroll
        for (int k = 0; k < 16; ++k) a = fmaf(nv[k], pw[k], a);
        xform[link * 64 + (c & 15) * 4 + (c >> 4)] = a;
    }
}

extern "C" void kernel_launch(void* const* d_in, const int* in_sizes, int n_in,
                              void* d_out, int out_size, void* d_ws, size_t ws_size,
                              hipStream_t stream) {
    const float* flow_traffic = (const float*)d_in[0];
    const float* flow_packets = (const float*)d_in[1];
    const float* max_link_load = (const float*)d_in[2];
    const float* flow_pkts_per_burst = (const float*)d_in[3];
    const float* flow_bitrate_per_burst = (const float*)d_in[4];
    const float* flow_packet_size = (const float*)d_in[5];
    const float* flow_type = (const float*)d_in[6];
    const float* flow_ipg_mean = (const float*)d_in[7];
    const float* ibg = (const float*)d_in[8];
    const float* flow_p90 = (const float*)d_in[9];
    const float* rate = (const float*)d_in[10];
    const float* flow_ipg_var = (const float*)d_in[11];
    const float* link_capacity = (const float*)d_in[12];
    const float* fe_W1 = (const float*)d_in[13];
    const float* fe_b1 = (const float*)d_in[14];
    const float* fe_W2 = (const float*)d_in[15];
    const float* fe_b2 = (const float*)d_in[16];
    const float* le_W1 = (const float*)d_in[17];
    const float* le_b1 = (const float*)d_in[18];
    const float* le_W2 = (const float*)d_in[19];
    const float* le_b2 = (const float*)d_in[20];
    const float* att_W = (const float*)d_in[21];
    const float* att_b = (const float*)d_in[22];
    const float* pgru_Wk = (const float*)d_in[23];
    const float* pgru_Wr = (const float*)d_in[24];
    const float* pgru_b = (const float*)d_in[25];
    const float* lgru_Wk = (const float*)d_in[26];
    const float* lgru_Wr = (const float*)d_in[27];
    const float* lgru_b = (const float*)d_in[28];
    const float* ro_W1 = (const float*)d_in[29];
    const float* ro_b1 = (const float*)d_in[30];
    const float* ro_W2 = (const float*)d_in[31];
    const float* ro_b2 = (const float*)d_in[32];
    const float* ro_W3 = (const float*)d_in[33];
    const float* ro_b3 = (const float*)d_in[34];
    const int* flow_length = (const int*)d_in[35];
    const int* l2p = (const int*)d_in[36];
    const int* p2l = (const int*)d_in[37];

    float* ws = (float*)d_ws;
    float* path_state = ws;                      // 800000
    float* link_state = ws + 800000;             // 80000
    float* sv = ws + 880000;                     // 7200000  [pos][flow][16]
    float* load = ws + 8080000;                  // 5000
    float* xform = ws + 8085000;                 // 320000   [link][16][4]
    float* Wpk = ws + 8405000;                   // 768
    float* Wa_t = ws + 8405768;                  // 256
    float* lWk_t = ws + 8406024;                 // 768
    float* lWr_t = ws + 8406792;                 // 768
    float* pWk_t = ws + 8407560;                 // 768
    if (ws_size < (size_t)8408328 * 4) return;

    k_prep<<<13, 256, 0, stream>>>(pgru_Wr, att_W, lgru_Wk, lgru_Wr, pgru_Wk,
                                   Wpk, Wa_t, lWk_t, lWr_t, pWk_t);
    k_load<<<(N_LINKS * 64 + 255) / 256, 256, 0, stream>>>(p2l, flow_traffic,
                                                           link_capacity, load);
    k_flow_init<<<(N_FLOWS + 255) / 256, 256, 0, stream>>>(
        flow_traffic, flow_packets, ibg, rate, flow_p90, flow_packet_size,
        flow_bitrate_per_burst, flow_ipg_mean, flow_ipg_var, flow_pkts_per_burst,
        flow_length, flow_type, fe_W1, fe_b1, fe_W2, fe_b2, path_state);
    k_link_init<<<(N_LINKS + 255) / 256, 256, 0, stream>>>(
        link_capacity, load, max_link_load, le_W1, le_b1, le_W2, le_b2,
        pgru_Wk, pgru_b, link_state, xform);

    int fp_grid = (N_FLOWS + 31) / 32;
    for (int it = 0; it < ITERS - 1; ++it) {
        k_flow_pass<false><<<fp_grid, 256, 0, stream>>>(
            l2p, xform, path_state, sv, Wpk, pgru_b, Wa_t, att_b,
            nullptr, nullptr, nullptr, nullptr, nullptr, nullptr, nullptr,
            nullptr);
        k_link_pass<<<N_LINKS / 4, 256, 0, stream>>>(
            p2l, sv, link_state, lWk_t, lWr_t, lgru_b, pWk_t, pgru_b, xform);
    }
    // final iteration: no sv / no link update needed; fuse readout.
    k_flow_pass<true><<<fp_grid, 256, 0, stream>>>(
        l2p, xform, path_state, sv, Wpk, pgru_b, Wa_t, att_b,
        link_capacity, ro_W1, ro_b1, ro_W2, ro_b2, ro_W3, ro_b3,
        (float*)d_out);
}

// Round 7
// 586.891 us; speedup vs baseline: 5.2419x; 1.1183x over previous
//
#include <hip/hip_runtime.h>
#include <hip/hip_bf16.h>

#define N_FLOWS 50000
#define N_LINKS 5000
#define LPATH 8
#define PLINK 80
#define DIM 16
#define ITERS 12

typedef __attribute__((ext_vector_type(4))) float f32x4;

// ds_swizzle BitMode: offset = (xor<<10) | (or<<5) | and  (within 32-lane half)
#define SWZ(x, pat) __int_as_float(__builtin_amdgcn_ds_swizzle(__float_as_int(x), (pat)))

// fast reciprocal: v_rcp_f32 (1 inst vs ~10-inst IEEE div sequence)
__device__ __forceinline__ float rcp_(float x) { return __builtin_amdgcn_rcpf(x); }
__device__ __forceinline__ float sigmoid_(float x) { return rcp_(1.f + __expf(-x)); }
__device__ __forceinline__ float tanh_(float x) { return 1.f - 2.f * rcp_(1.f + __expf(2.f * x)); }
__device__ __forceinline__ float selu_(float x) {
    const float sc = 1.0507009873554805f, al = 1.6732632423543772f;
    return x > 0.f ? sc * x : sc * al * expm1f(x);
}
__device__ __forceinline__ float softplus_(float x) {
    return fmaxf(x, 0.f) + log1pf(__expf(-fabsf(x)));
}

// ---- one-time weight repack (transpose to per-lane-contiguous rows) ------
__global__ __launch_bounds__(256) void k_prep(
    const float* __restrict__ pWr, const float* __restrict__ attW,
    const float* __restrict__ lWk, const float* __restrict__ lWr,
    const float* __restrict__ pWk,
    float* __restrict__ Wpk, float* __restrict__ Wa_t,
    float* __restrict__ lWk_t, float* __restrict__ lWr_t,
    float* __restrict__ pWk_t) {
    int i = blockIdx.x * 256 + threadIdx.x;
    if (i < 768) {
        int j = i / 48, r = i % 48;
        Wpk[i] = pWr[(r % 16) * 48 + (r / 16) * 16 + j];
    } else if (i < 1024) {
        int t = i - 768;
        Wa_t[t] = attW[(t % 16) * 16 + (t / 16)];
    } else if (i < 1792) {
        int t = i - 1024;
        int j = t / 48, r = t % 48;
        lWk_t[t] = lWk[(r % 16) * 48 + (r / 16) * 16 + j];
    } else if (i < 2560) {
        int t = i - 1792;
        int j = t / 48, r = t % 48;
        lWr_t[t] = lWr[(r % 16) * 48 + (r / 16) * 16 + j];
    } else if (i < 3328) {
        int t = i - 2560;
        pWk_t[t] = pWk[(t % 16) * 48 + (t / 16)];
    }
}

// ---- load per link -------------------------------------------------------
__global__ __launch_bounds__(256) void k_load(const int* __restrict__ p2l,
                                              const float* __restrict__ flow_traffic,
                                              const float* __restrict__ link_capacity,
                                              float* __restrict__ load) {
    int wave = (blockIdx.x * 256 + threadIdx.x) >> 6;
    int lane = threadIdx.x & 63;
    if (wave >= N_LINKS) return;
    float s = 0.f;
    for (int p = lane; p < PLINK; p += 64) {
        int flow = p2l[(wave * PLINK + p) * 2];
        s += flow_traffic[flow];
    }
#pragma unroll
    for (int off = 32; off; off >>= 1) s += __shfl_xor(s, off, 64);
    if (lane == 0) load[wave] = s / (link_capacity[wave] * 1e9f);
}

// ---- flow embedding ------------------------------------------------------
__global__ __launch_bounds__(256) void k_flow_init(
    const float* __restrict__ flow_traffic, const float* __restrict__ flow_packets,
    const float* __restrict__ ibg, const float* __restrict__ rate,
    const float* __restrict__ p90, const float* __restrict__ pkt_size,
    const float* __restrict__ bitrate_pb, const float* __restrict__ ipg_mean,
    const float* __restrict__ ipg_var, const float* __restrict__ pkts_pb,
    const int* __restrict__ flow_length, const float* __restrict__ flow_type,
    const float* __restrict__ W1, const float* __restrict__ b1,
    const float* __restrict__ W2, const float* __restrict__ b2,
    float* __restrict__ path_state) {
    int f = blockIdx.x * 256 + threadIdx.x;
    if (f >= N_FLOWS) return;
    float feats[13];
    feats[0] = (flow_traffic[f] - 0.1f) * 2.f;
    feats[1] = (flow_packets[f] - 0.1f) * 2.f;
    feats[2] = (ibg[f] - 0.1f) * 2.f;
    feats[3] = (rate[f] - 0.1f) * 2.f;
    feats[4] = (p90[f] - 0.1f) * 2.f;
    feats[5] = (pkt_size[f] - 0.1f) * 2.f;
    feats[6] = (bitrate_pb[f] - 0.1f) * 2.f;
    feats[7] = (ipg_mean[f] - 0.1f) * 2.f;
    feats[8] = (ipg_var[f] - 0.1f) * 2.f;
    feats[9] = (pkts_pb[f] - 0.1f) * 2.f;
    feats[10] = (float)flow_length[f];
    feats[11] = flow_type[f * 2 + 0];
    feats[12] = flow_type[f * 2 + 1];
    float h1[DIM];
#pragma unroll
    for (int j = 0; j < DIM; ++j) {
        float a = b1[j];
#pragma unroll
        for (int k = 0; k < 13; ++k) a = fmaf(feats[k], W1[k * DIM + j], a);
        h1[j] = selu_(a);
    }
#pragma unroll
    for (int j = 0; j < DIM; ++j) {
        float a = b2[j];
#pragma unroll
        for (int k = 0; k < DIM; ++k) a = fmaf(h1[k], W2[k * DIM + j], a);
        path_state[f * DIM + j] = selu_(a);
    }
}

// ---- link embedding + xform precompute (padded [link][j][4] layout) ------
__global__ __launch_bounds__(256) void k_link_init(
    const float* __restrict__ link_capacity, const float* __restrict__ load,
    const float* __restrict__ max_link_load,
    const float* __restrict__ W1, const float* __restrict__ b1,
    const float* __restrict__ W2, const float* __restrict__ b2,
    const float* __restrict__ pWk, const float* __restrict__ pb,
    float* __restrict__ link_state, float* __restrict__ xform) {
    int l = blockIdx.x * 256 + threadIdx.x;
    if (l >= N_LINKS) return;
    float feats[3];
    feats[0] = (link_capacity[l] - 0.1f) * 2.f;
    feats[1] = load[l];
    feats[2] = load[l] / max_link_load[0];
    float h1[DIM];
#pragma unroll
    for (int j = 0; j < DIM; ++j) {
        float a = b1[j];
#pragma unroll
        for (int k = 0; k < 3; ++k) a = fmaf(feats[k], W1[k * DIM + j], a);
        h1[j] = selu_(a);
    }
    float h2[DIM];
#pragma unroll
    for (int j = 0; j < DIM; ++j) {
        float a = b2[j];
#pragma unroll
        for (int k = 0; k < DIM; ++k) a = fmaf(h1[k], W2[k * DIM + j], a);
        h2[j] = selu_(a);
        link_state[l * DIM + j] = h2[j];
    }
#pragma unroll
    for (int c = 0; c < 3 * DIM; ++c) {
        float a = pb[c];
#pragma unroll
        for (int k = 0; k < DIM; ++k) a = fmaf(h2[k], pWk[k * 48 + c], a);
        xform[l * 64 + (c & 15) * 4 + (c >> 4)] = a;
    }
}

// ---- flow pass: 2 flows per 16-lane group (2 independent GRU chains) -----
// Lane j of group gi handles hidden dim j of flows base+gi and base+16+gi.
template <bool LAST>
__global__ __launch_bounds__(256) void k_flow_pass(
    const int* __restrict__ l2p, const float* __restrict__ xform,
    float* __restrict__ path_state, float* __restrict__ sv,
    const float* __restrict__ Wpk, const float* __restrict__ b,
    const float* __restrict__ Wa_t, const float* __restrict__ attB,
    const float* __restrict__ link_capacity,
    const float* __restrict__ roW1, const float* __restrict__ rob1,
    const float* __restrict__ roW2, const float* __restrict__ rob2,
    const float* __restrict__ roW3, const float* __restrict__ rob3,
    float* __restrict__ out) {
    __shared__ float hbuf[2][16][16];
    __shared__ float shist[LAST ? 32 : 1][LPATH + 1][17];
    int tid = threadIdx.x;
    int gi = tid >> 4, j = tid & 15;
    int base = blockIdx.x * 32;
    int fA = base + gi;
    int fB = base + 16 + gi;
    int fAc = fA < N_FLOWS ? fA : N_FLOWS - 1;
    int fBc = fB < N_FLOWS ? fB : N_FLOWS - 1;
    float wz[16], wr[16], wh[16], wa[16];
#pragma unroll
    for (int q = 0; q < 4; ++q) {
        f32x4 vz = ((const f32x4*)(Wpk + j * 48))[q];
        f32x4 vr = ((const f32x4*)(Wpk + j * 48 + 16))[q];
        f32x4 vh = ((const f32x4*)(Wpk + j * 48 + 32))[q];
        f32x4 va = ((const f32x4*)(Wa_t + j * 16))[q];
#pragma unroll
        for (int e = 0; e < 4; ++e) {
            wz[q * 4 + e] = vz[e];
            wr[q * 4 + e] = vr[e];
            wh[q * 4 + e] = vh[e];
            wa[q * 4 + e] = va[e];
        }
    }
    float b1z = b[48 + j], b1r = b[64 + j], b1h = b[80 + j], ab = attB[j];
    int linksA[LPATH], linksB[LPATH];
    {
        int4 a0 = ((const int4*)(l2p + fAc * LPATH))[0];
        int4 a1 = ((const int4*)(l2p + fAc * LPATH))[1];
        int4 c0 = ((const int4*)(l2p + fBc * LPATH))[0];
        int4 c1 = ((const int4*)(l2p + fBc * LPATH))[1];
        linksA[0] = a0.x; linksA[1] = a0.y; linksA[2] = a0.z; linksA[3] = a0.w;
        linksA[4] = a1.x; linksA[5] = a1.y; linksA[6] = a1.z; linksA[7] = a1.w;
        linksB[0] = c0.x; linksB[1] = c0.y; linksB[2] = c0.z; linksB[3] = c0.w;
        linksB[4] = c1.x; linksB[5] = c1.y; linksB[6] = c1.z; linksB[7] = c1.w;
    }
    const f32x4* xf = (const f32x4*)xform;
    float hA = path_state[fAc * DIM + j];
    float hB = path_state[fBc * DIM + j];
    f32x4 nxA = xf[linksA[0] * 16 + j];
    f32x4 nxB = xf[linksB[0] * 16 + j];
#pragma unroll
    for (int p = 0; p <= LPATH; ++p) {
        hbuf[0][gi][j] = hA;
        hbuf[1][gi][j] = hB;
        float ha[16], hb[16];
#pragma unroll
        for (int q = 0; q < 4; ++q) {
            f32x4 vA = ((const f32x4*)hbuf[0][gi])[q];
            f32x4 vB = ((const f32x4*)hbuf[1][gi])[q];
#pragma unroll
            for (int e = 0; e < 4; ++e) {
                ha[q * 4 + e] = vA[e];
                hb[q * 4 + e] = vB[e];
            }
        }
        if constexpr (!LAST) {
            float attA = ab, attB_ = ab;
#pragma unroll
            for (int k = 0; k < 16; ++k) {
                attA = fmaf(ha[k], wa[k], attA);
                attB_ = fmaf(hb[k], wa[k], attB_);
            }
            attA = attA > 0.f ? attA : 0.01f * attA;
            attB_ = attB_ > 0.f ? attB_ : 0.01f * attB_;
            float mA = attA, mB = attB_;
            mA = fmaxf(mA, SWZ(mA, 0x041F)); mB = fmaxf(mB, SWZ(mB, 0x041F));
            mA = fmaxf(mA, SWZ(mA, 0x081F)); mB = fmaxf(mB, SWZ(mB, 0x081F));
            mA = fmaxf(mA, SWZ(mA, 0x101F)); mB = fmaxf(mB, SWZ(mB, 0x101F));
            mA = fmaxf(mA, SWZ(mA, 0x201F)); mB = fmaxf(mB, SWZ(mB, 0x201F));
            float eA = __expf(attA - mA), eB = __expf(attB_ - mB);
            float sA = eA, sB = eB;
            sA += SWZ(sA, 0x041F); sB += SWZ(sB, 0x041F);
            sA += SWZ(sA, 0x081F); sB += SWZ(sB, 0x081F);
            sA += SWZ(sA, 0x101F); sB += SWZ(sB, 0x101F);
            sA += SWZ(sA, 0x201F); sB += SWZ(sB, 0x201F);
            sv[p * (N_FLOWS * DIM) + fA * DIM + j] = eA * rcp_(sA) * hA;
            if (fB < N_FLOWS)
                sv[p * (N_FLOWS * DIM) + fB * DIM + j] = eB * rcp_(sB) * hB;
        } else {
            shist[gi][p][j] = hA;
            shist[gi + 16][p][j] = hB;
        }
        if (p < LPATH) {
            f32x4 cxA = nxA, cxB = nxB;
            if (p + 1 < LPATH) {
                nxA = xf[linksA[p + 1] * 16 + j];
                nxB = xf[linksB[p + 1] * 16 + j];
            }
            float gzA = b1z, grA = b1r, ghA = b1h;
            float gzB = b1z, grB = b1r, ghB = b1h;
#pragma unroll
            for (int k = 0; k < 16; ++k) {
                gzA = fmaf(ha[k], wz[k], gzA);
                grA = fmaf(ha[k], wr[k], grA);
                ghA = fmaf(ha[k], wh[k], ghA);
                gzB = fmaf(hb[k], wz[k], gzB);
                grB = fmaf(hb[k], wr[k], grB);
                ghB = fmaf(hb[k], wh[k], ghB);
            }
            float zA = sigmoid_(cxA[0] + gzA);
            float rA = sigmoid_(cxA[1] + grA);
            float cA = tanh_(fmaf(rA, ghA, cxA[2]));
            hA = zA * hA + (1.f - zA) * cA;
            float zB = sigmoid_(cxB[0] + gzB);
            float rB = sigmoid_(cxB[1] + grB);
            float cB = tanh_(fmaf(rB, ghB, cxB[2]));
            hB = zB * hB + (1.f - zB) * cB;
        }
    }
    if constexpr (!LAST) {
        path_state[fA * DIM + j] = hA;
        if (fB < N_FLOWS) path_state[fB * DIM + j] = hB;
    } else {
        __syncthreads();
        {  // 32 flows x 8 positions = 256 threads
            int fl = tid >> 3, t = tid & 7;
            int fg = base + fl;
            const float* s = shist[fl][t + 1];
            float h1[8];
#pragma unroll
            for (int m_ = 0; m_ < 8; ++m_) {
                float a = rob1[m_];
#pragma unroll
                for (int k = 0; k < 16; ++k) a = fmaf(s[k], roW1[k * 8 + m_], a);
                h1[m_] = selu_(a);
            }
            float h2[4];
#pragma unroll
            for (int q = 0; q < 4; ++q) {
                float a = rob2[q];
#pragma unroll
                for (int m_ = 0; m_ < 8; ++m_) a = fmaf(h1[m_], roW2[m_ * 4 + q], a);
                h2[q] = selu_(a);
            }
            float o = rob3[0];
#pragma unroll
            for (int q = 0; q < 4; ++q) o = fmaf(h2[q], roW3[q], o);
            o = softplus_(o);
            int fgc = fg < N_FLOWS ? fg : N_FLOWS - 1;
            int link = l2p[fgc * LPATH + t];
            float v = o * rcp_(link_capacity[link]);
            v += SWZ(v, 0x041F);
            v += SWZ(v, 0x081F);
            v += SWZ(v, 0x101F);
            if (t == 0 && fg < N_FLOWS) out[fg] = v;
        }
    }
}

// ---- link pass: gather-sum of sv + link GRU + fused xform ----------------
// 4 links per 256-block, one wave per link (16 j-lanes x 4 p-slices).
__global__ __launch_bounds__(256, 4) void k_link_pass(
    const int* __restrict__ p2l, const float* __restrict__ sv,
    float* __restrict__ link_state,
    const float* __restrict__ lWk_t, const float* __restrict__ lWr_t,
    const float* __restrict__ b,
    const float* __restrict__ pWk_t, const float* __restrict__ pb,
    float* __restrict__ xform) {
    __shared__ float xb_[4][16];
    __shared__ float hb_[4][16];
    int tid = threadIdx.x;
    int li = tid >> 6;
    int lane = tid & 63;
    int sl = lane >> 4, j = lane & 15;
    int link = blockIdx.x * 4 + li;
    float ps = 0.f;
#pragma unroll 4
    for (int i = 0; i < PLINK / 4; ++i) {
        int p = sl + 4 * i;
        int2 fp = ((const int2*)p2l)[link * PLINK + p];
        ps += sv[fp.y * (N_FLOWS * DIM) + fp.x * DIM + j];
    }
    ps += __shfl_xor(ps, 16, 64);
    ps += __shfl_xor(ps, 32, 64);
    float h = link_state[link * DIM + j];
    if (sl == 0) { xb_[li][j] = ps; hb_[li][j] = h; }
    float xv[16], hv[16];
#pragma unroll
    for (int q = 0; q < 4; ++q) {
        f32x4 x4 = ((const f32x4*)xb_[li])[q];
        f32x4 h4 = ((const f32x4*)hb_[li])[q];
#pragma unroll
        for (int e = 0; e < 4; ++e) { xv[q * 4 + e] = x4[e]; hv[q * 4 + e] = h4[e]; }
    }
    float az = b[j], ar = b[16 + j], ah = b[32 + j];
    float gz = b[48 + j], gr = b[64 + j], gh = b[80 + j];
    const float* kz = lWk_t + j * 48;
    const float* rz = lWr_t + j * 48;
#pragma unroll
    for (int k = 0; k < 16; ++k) {
        az = fmaf(xv[k], kz[k], az);
        ar = fmaf(xv[k], kz[16 + k], ar);
        ah = fmaf(xv[k], kz[32 + k], ah);
        gz = fmaf(hv[k], rz[k], gz);
        gr = fmaf(hv[k], rz[16 + k], gr);
        gh = fmaf(hv[k], rz[32 + k], gh);
    }
    float z = sigmoid_(az + gz);
    float r = sigmoid_(ar + gr);
    float hn = z * h + (1.f - z) * tanh_(fmaf(r, gh, ah));
    if (sl == 0) {
        link_state[link * DIM + j] = hn;
        hb_[li][j] = hn;  // re-broadcast new state for xform
    }
    float nv[16];
#pragma unroll
    for (int q = 0; q < 4; ++q) {
        f32x4 n4 = ((const f32x4*)hb_[li])[q];
#pragma unroll
        for (int e = 0; e < 4; ++e) nv[q * 4 + e] = n4[e];
    }
    int c = lane;
    if (c < 48) {
        const float* pw = pWk_t + c * 16;
        float a = pb[c];
#pragma unroll
        for (int k = 0; k < 16; ++k) a = fmaf(nv[k], pw[k], a);
        xform[link * 64 + (c & 15) * 4 + (c >> 4)] = a;
    }
}

extern "C" void kernel_launch(void* const* d_in, const int* in_sizes, int n_in,
                              void* d_out, int out_size, void* d_ws, size_t ws_size,
                              hipStream_t stream) {
    const float* flow_traffic = (const float*)d_in[0];
    const float* flow_packets = (const float*)d_in[1];
    const float* max_link_load = (const float*)d_in[2];
    const float* flow_pkts_per_burst = (const float*)d_in[3];
    const float* flow_bitrate_per_burst = (const float*)d_in[4];
    const float* flow_packet_size = (const float*)d_in[5];
    const float* flow_type = (const float*)d_in[6];
    const float* flow_ipg_mean = (const float*)d_in[7];
    const float* ibg = (const float*)d_in[8];
    const float* flow_p90 = (const float*)d_in[9];
    const float* rate = (const float*)d_in[10];
    const float* flow_ipg_var = (const float*)d_in[11];
    const float* link_capacity = (const float*)d_in[12];
    const float* fe_W1 = (const float*)d_in[13];
    const float* fe_b1 = (const float*)d_in[14];
    const float* fe_W2 = (const float*)d_in[15];
    const float* fe_b2 = (const float*)d_in[16];
    const float* le_W1 = (const float*)d_in[17];
    const float* le_b1 = (const float*)d_in[18];
    const float* le_W2 = (const float*)d_in[19];
    const float* le_b2 = (const float*)d_in[20];
    const float* att_W = (const float*)d_in[21];
    const float* att_b = (const float*)d_in[22];
    const float* pgru_Wk = (const float*)d_in[23];
    const float* pgru_Wr = (const float*)d_in[24];
    const float* pgru_b = (const float*)d_in[25];
    const float* lgru_Wk = (const float*)d_in[26];
    const float* lgru_Wr = (const float*)d_in[27];
    const float* lgru_b = (const float*)d_in[28];
    const float* ro_W1 = (const float*)d_in[29];
    const float* ro_b1 = (const float*)d_in[30];
    const float* ro_W2 = (const float*)d_in[31];
    const float* ro_b2 = (const float*)d_in[32];
    const float* ro_W3 = (const float*)d_in[33];
    const float* ro_b3 = (const float*)d_in[34];
    const int* flow_length = (const int*)d_in[35];
    const int* l2p = (const int*)d_in[36];
    const int* p2l = (const int*)d_in[37];

    float* ws = (float*)d_ws;
    float* path_state = ws;                      // 800000
    float* link_state = ws + 800000;             // 80000
    float* sv = ws + 880000;                     // 7200000  [pos][flow][16]
    float* load = ws + 8080000;                  // 5000
    float* xform = ws + 8085000;                 // 320000   [link][16][4]
    float* Wpk = ws + 8405000;                   // 768
    float* Wa_t = ws + 8405768;                  // 256
    float* lWk_t = ws + 8406024;                 // 768
    float* lWr_t = ws + 8406792;                 // 768
    float* pWk_t = ws + 8407560;                 // 768
    if (ws_size < (size_t)8408328 * 4) return;

    k_prep<<<13, 256, 0, stream>>>(pgru_Wr, att_W, lgru_Wk, lgru_Wr, pgru_Wk,
                                   Wpk, Wa_t, lWk_t, lWr_t, pWk_t);
    k_load<<<(N_LINKS * 64 + 255) / 256, 256, 0, stream>>>(p2l, flow_traffic,
                                                           link_capacity, load);
    k_flow_init<<<(N_FLOWS + 255) / 256, 256, 0, stream>>>(
        flow_traffic, flow_packets, ibg, rate, flow_p90, flow_packet_size,
        flow_bitrate_per_burst, flow_ipg_mean, flow_ipg_var, flow_pkts_per_burst,
        flow_length, flow_type, fe_W1, fe_b1, fe_W2, fe_b2, path_state);
    k_link_init<<<(N_LINKS + 255) / 256, 256, 0, stream>>>(
        link_capacity, load, max_link_load, le_W1, le_b1, le_W2, le_b2,
        pgru_Wk, pgru_b, link_state, xform);

    int fp_grid = (N_FLOWS + 31) / 32;
    for (int it = 0; it < ITERS - 1; ++it) {
        k_flow_pass<false><<<fp_grid, 256, 0, stream>>>(
            l2p, xform, path_state, sv, Wpk, pgru_b, Wa_t, att_b,
            nullptr, nullptr, nullptr, nullptr, nullptr, nullptr, nullptr,
            nullptr);
        k_link_pass<<<N_LINKS / 4, 256, 0, stream>>>(
            p2l, sv, link_state, lWk_t, lWr_t, lgru_b, pWk_t, pgru_b, xform);
    }
    // final iteration: no sv / no link update needed; fuse readout.
    k_flow_pass<true><<<fp_grid, 256, 0, stream>>>(
        l2p, xform, path_state, sv, Wpk, pgru_b, Wa_t, att_b,
        link_capacity, ro_W1, ro_b1, ro_W2, ro_b2, ro_W3, ro_b3,
        (float*)d_out);
}

// Round 8
// 530.702 us; speedup vs baseline: 5.7969x; 1.1059x over previous
//
#include <hip/hip_runtime.h>
#include <hip/hip_bf16.h>

#define N_FLOWS 50000
#define N_LINKS 5000
#define LPATH 8
#define PLINK 80
#define DIM 16
#define ITERS 12

typedef __attribute__((ext_vector_type(4))) float f32x4;

// ds_swizzle BitMode: offset = (xor<<10) | (or<<5) | and  (within 32-lane half)
#define SWZ(x, pat) __int_as_float(__builtin_amdgcn_ds_swizzle(__float_as_int(x), (pat)))

// DPP row_ror move: dst lane gets value rotated within its 16-lane row.
// VALU-pipe cross-lane (GCNDPPCombine fuses into v_{add,max}_f32_dpp).
template <int CTRL>
__device__ __forceinline__ float dppmov_(float x) {
    return __int_as_float(__builtin_amdgcn_update_dpp(
        0, __float_as_int(x), CTRL, 0xF, 0xF, true));
}
#define ROR1 0x121
#define ROR2 0x122
#define ROR4 0x124
#define ROR8 0x128

// fast reciprocal: v_rcp_f32 (1 inst vs ~10-inst IEEE div sequence)
__device__ __forceinline__ float rcp_(float x) { return __builtin_amdgcn_rcpf(x); }
__device__ __forceinline__ float sigmoid_(float x) { return rcp_(1.f + __expf(-x)); }
__device__ __forceinline__ float tanh_(float x) { return 1.f - 2.f * rcp_(1.f + __expf(2.f * x)); }
__device__ __forceinline__ float selu_(float x) {
    const float sc = 1.0507009873554805f, al = 1.6732632423543772f;
    return x > 0.f ? sc * x : sc * al * expm1f(x);
}
__device__ __forceinline__ float softplus_(float x) {
    return fmaxf(x, 0.f) + log1pf(__expf(-fabsf(x)));
}

// ---- one-time weight repack (transpose to per-lane-contiguous rows) ------
__global__ __launch_bounds__(256) void k_prep(
    const float* __restrict__ pWr, const float* __restrict__ attW,
    const float* __restrict__ lWk, const float* __restrict__ lWr,
    const float* __restrict__ pWk,
    float* __restrict__ Wpk, float* __restrict__ Wa_t,
    float* __restrict__ lWk_t, float* __restrict__ lWr_t,
    float* __restrict__ pWk_t) {
    int i = blockIdx.x * 256 + threadIdx.x;
    if (i < 768) {
        int j = i / 48, r = i % 48;
        Wpk[i] = pWr[(r % 16) * 48 + (r / 16) * 16 + j];
    } else if (i < 1024) {
        int t = i - 768;
        Wa_t[t] = attW[(t % 16) * 16 + (t / 16)];
    } else if (i < 1792) {
        int t = i - 1024;
        int j = t / 48, r = t % 48;
        lWk_t[t] = lWk[(r % 16) * 48 + (r / 16) * 16 + j];
    } else if (i < 2560) {
        int t = i - 1792;
        int j = t / 48, r = t % 48;
        lWr_t[t] = lWr[(r % 16) * 48 + (r / 16) * 16 + j];
    } else if (i < 3328) {
        int t = i - 2560;
        pWk_t[t] = pWk[(t % 16) * 48 + (t / 16)];
    }
}

// ---- load per link -------------------------------------------------------
__global__ __launch_bounds__(256) void k_load(const int* __restrict__ p2l,
                                              const float* __restrict__ flow_traffic,
                                              const float* __restrict__ link_capacity,
                                              float* __restrict__ load) {
    int wave = (blockIdx.x * 256 + threadIdx.x) >> 6;
    int lane = threadIdx.x & 63;
    if (wave >= N_LINKS) return;
    float s = 0.f;
    for (int p = lane; p < PLINK; p += 64) {
        int flow = p2l[(wave * PLINK + p) * 2];
        s += flow_traffic[flow];
    }
#pragma unroll
    for (int off = 32; off; off >>= 1) s += __shfl_xor(s, off, 64);
    if (lane == 0) load[wave] = s / (link_capacity[wave] * 1e9f);
}

// ---- flow embedding ------------------------------------------------------
__global__ __launch_bounds__(256) void k_flow_init(
    const float* __restrict__ flow_traffic, const float* __restrict__ flow_packets,
    const float* __restrict__ ibg, const float* __restrict__ rate,
    const float* __restrict__ p90, const float* __restrict__ pkt_size,
    const float* __restrict__ bitrate_pb, const float* __restrict__ ipg_mean,
    const float* __restrict__ ipg_var, const float* __restrict__ pkts_pb,
    const int* __restrict__ flow_length, const float* __restrict__ flow_type,
    const float* __restrict__ W1, const float* __restrict__ b1,
    const float* __restrict__ W2, const float* __restrict__ b2,
    float* __restrict__ path_state) {
    int f = blockIdx.x * 256 + threadIdx.x;
    if (f >= N_FLOWS) return;
    float feats[13];
    feats[0] = (flow_traffic[f] - 0.1f) * 2.f;
    feats[1] = (flow_packets[f] - 0.1f) * 2.f;
    feats[2] = (ibg[f] - 0.1f) * 2.f;
    feats[3] = (rate[f] - 0.1f) * 2.f;
    feats[4] = (p90[f] - 0.1f) * 2.f;
    feats[5] = (pkt_size[f] - 0.1f) * 2.f;
    feats[6] = (bitrate_pb[f] - 0.1f) * 2.f;
    feats[7] = (ipg_mean[f] - 0.1f) * 2.f;
    feats[8] = (ipg_var[f] - 0.1f) * 2.f;
    feats[9] = (pkts_pb[f] - 0.1f) * 2.f;
    feats[10] = (float)flow_length[f];
    feats[11] = flow_type[f * 2 + 0];
    feats[12] = flow_type[f * 2 + 1];
    float h1[DIM];
#pragma unroll
    for (int j = 0; j < DIM; ++j) {
        float a = b1[j];
#pragma unroll
        for (int k = 0; k < 13; ++k) a = fmaf(feats[k], W1[k * DIM + j], a);
        h1[j] = selu_(a);
    }
#pragma unroll
    for (int j = 0; j < DIM; ++j) {
        float a = b2[j];
#pragma unroll
        for (int k = 0; k < DIM; ++k) a = fmaf(h1[k], W2[k * DIM + j], a);
        path_state[f * DIM + j] = selu_(a);
    }
}

// ---- link embedding + xform precompute (padded [link][j][4] layout) ------
__global__ __launch_bounds__(256) void k_link_init(
    const float* __restrict__ link_capacity, const float* __restrict__ load,
    const float* __restrict__ max_link_load,
    const float* __restrict__ W1, const float* __restrict__ b1,
    const float* __restrict__ W2, const float* __restrict__ b2,
    const float* __restrict__ pWk, const float* __restrict__ pb,
    float* __restrict__ link_state, float* __restrict__ xform) {
    int l = blockIdx.x * 256 + threadIdx.x;
    if (l >= N_LINKS) return;
    float feats[3];
    feats[0] = (link_capacity[l] - 0.1f) * 2.f;
    feats[1] = load[l];
    feats[2] = load[l] / max_link_load[0];
    float h1[DIM];
#pragma unroll
    for (int j = 0; j < DIM; ++j) {
        float a = b1[j];
#pragma unroll
        for (int k = 0; k < 3; ++k) a = fmaf(feats[k], W1[k * DIM + j], a);
        h1[j] = selu_(a);
    }
    float h2[DIM];
#pragma unroll
    for (int j = 0; j < DIM; ++j) {
        float a = b2[j];
#pragma unroll
        for (int k = 0; k < DIM; ++k) a = fmaf(h1[k], W2[k * DIM + j], a);
        h2[j] = selu_(a);
        link_state[l * DIM + j] = h2[j];
    }
#pragma unroll
    for (int c = 0; c < 3 * DIM; ++c) {
        float a = pb[c];
#pragma unroll
        for (int k = 0; k < DIM; ++k) a = fmaf(h2[k], pWk[k * 48 + c], a);
        xform[l * 64 + (c & 15) * 4 + (c >> 4)] = a;
    }
}

// ---- flow pass: 2 flows per 16-lane group (2 independent GRU chains) -----
// Lane j of group gi handles hidden dim j of flows base+gi and base+16+gi.
// Softmax reductions use DPP row_ror (VALU pipe, ~4cy) instead of ds_swizzle.
template <bool LAST>
__global__ __launch_bounds__(256) void k_flow_pass(
    const int* __restrict__ l2p, const float* __restrict__ xform,
    float* __restrict__ path_state, float* __restrict__ sv,
    const float* __restrict__ Wpk, const float* __restrict__ b,
    const float* __restrict__ Wa_t, const float* __restrict__ attB,
    const float* __restrict__ link_capacity,
    const float* __restrict__ roW1, const float* __restrict__ rob1,
    const float* __restrict__ roW2, const float* __restrict__ rob2,
    const float* __restrict__ roW3, const float* __restrict__ rob3,
    float* __restrict__ out) {
    // interleaved A/B, pad 18: rows 144B (16B-aligned), group-broadcast reads
    // land on disjoint bank quads (gi*36 dwords -> bank offset 4*gi).
    __shared__ float hbuf[16][18][2];
    __shared__ float shist[LAST ? 32 : 1][LPATH + 1][17];
    int tid = threadIdx.x;
    int gi = tid >> 4, j = tid & 15;
    int base = blockIdx.x * 32;
    int fA = base + gi;
    int fB = base + 16 + gi;
    int fAc = fA < N_FLOWS ? fA : N_FLOWS - 1;
    int fBc = fB < N_FLOWS ? fB : N_FLOWS - 1;
    float wz[16], wr[16], wh[16], wa[16];
#pragma unroll
    for (int q = 0; q < 4; ++q) {
        f32x4 vz = ((const f32x4*)(Wpk + j * 48))[q];
        f32x4 vr = ((const f32x4*)(Wpk + j * 48 + 16))[q];
        f32x4 vh = ((const f32x4*)(Wpk + j * 48 + 32))[q];
        f32x4 va = ((const f32x4*)(Wa_t + j * 16))[q];
#pragma unroll
        for (int e = 0; e < 4; ++e) {
            wz[q * 4 + e] = vz[e];
            wr[q * 4 + e] = vr[e];
            wh[q * 4 + e] = vh[e];
            wa[q * 4 + e] = va[e];
        }
    }
    float b1z = b[48 + j], b1r = b[64 + j], b1h = b[80 + j], ab = attB[j];
    int linksA[LPATH], linksB[LPATH];
    {
        int4 a0 = ((const int4*)(l2p + fAc * LPATH))[0];
        int4 a1 = ((const int4*)(l2p + fAc * LPATH))[1];
        int4 c0 = ((const int4*)(l2p + fBc * LPATH))[0];
        int4 c1 = ((const int4*)(l2p + fBc * LPATH))[1];
        linksA[0] = a0.x; linksA[1] = a0.y; linksA[2] = a0.z; linksA[3] = a0.w;
        linksA[4] = a1.x; linksA[5] = a1.y; linksA[6] = a1.z; linksA[7] = a1.w;
        linksB[0] = c0.x; linksB[1] = c0.y; linksB[2] = c0.z; linksB[3] = c0.w;
        linksB[4] = c1.x; linksB[5] = c1.y; linksB[6] = c1.z; linksB[7] = c1.w;
    }
    const f32x4* xf = (const f32x4*)xform;
    float hA = path_state[fAc * DIM + j];
    float hB = path_state[fBc * DIM + j];
    f32x4 nxA = xf[linksA[0] * 16 + j];
    f32x4 nxB = xf[linksB[0] * 16 + j];
#pragma unroll
    for (int p = 0; p <= LPATH; ++p) {
        *(float2*)&hbuf[gi][j][0] = make_float2(hA, hB);
        float ha[16], hb[16];
#pragma unroll
        for (int q = 0; q < 8; ++q) {
            f32x4 v = ((const f32x4*)&hbuf[gi][0][0])[q];
            ha[q * 2 + 0] = v[0];
            hb[q * 2 + 0] = v[1];
            ha[q * 2 + 1] = v[2];
            hb[q * 2 + 1] = v[3];
        }
        if constexpr (!LAST) {
            float attA = ab, attB_ = ab;
#pragma unroll
            for (int k = 0; k < 16; ++k) {
                attA = fmaf(ha[k], wa[k], attA);
                attB_ = fmaf(hb[k], wa[k], attB_);
            }
            attA = attA > 0.f ? attA : 0.01f * attA;
            attB_ = attB_ > 0.f ? attB_ : 0.01f * attB_;
            float mA = attA, mB = attB_;
            mA = fmaxf(mA, dppmov_<ROR1>(mA)); mB = fmaxf(mB, dppmov_<ROR1>(mB));
            mA = fmaxf(mA, dppmov_<ROR2>(mA)); mB = fmaxf(mB, dppmov_<ROR2>(mB));
            mA = fmaxf(mA, dppmov_<ROR4>(mA)); mB = fmaxf(mB, dppmov_<ROR4>(mB));
            mA = fmaxf(mA, dppmov_<ROR8>(mA)); mB = fmaxf(mB, dppmov_<ROR8>(mB));
            float eA = __expf(attA - mA), eB = __expf(attB_ - mB);
            float sA = eA, sB = eB;
            sA += dppmov_<ROR1>(sA); sB += dppmov_<ROR1>(sB);
            sA += dppmov_<ROR2>(sA); sB += dppmov_<ROR2>(sB);
            sA += dppmov_<ROR4>(sA); sB += dppmov_<ROR4>(sB);
            sA += dppmov_<ROR8>(sA); sB += dppmov_<ROR8>(sB);
            sv[p * (N_FLOWS * DIM) + fA * DIM + j] = eA * rcp_(sA) * hA;
            if (fB < N_FLOWS)
                sv[p * (N_FLOWS * DIM) + fB * DIM + j] = eB * rcp_(sB) * hB;
        } else {
            shist[gi][p][j] = hA;
            shist[gi + 16][p][j] = hB;
        }
        if (p < LPATH) {
            f32x4 cxA = nxA, cxB = nxB;
            if (p + 1 < LPATH) {
                nxA = xf[linksA[p + 1] * 16 + j];
                nxB = xf[linksB[p + 1] * 16 + j];
            }
            float gzA = b1z, grA = b1r, ghA = b1h;
            float gzB = b1z, grB = b1r, ghB = b1h;
#pragma unroll
            for (int k = 0; k < 16; ++k) {
                gzA = fmaf(ha[k], wz[k], gzA);
                grA = fmaf(ha[k], wr[k], grA);
                ghA = fmaf(ha[k], wh[k], ghA);
                gzB = fmaf(hb[k], wz[k], gzB);
                grB = fmaf(hb[k], wr[k], grB);
                ghB = fmaf(hb[k], wh[k], ghB);
            }
            float zA = sigmoid_(cxA[0] + gzA);
            float rA = sigmoid_(cxA[1] + grA);
            float cA = tanh_(fmaf(rA, ghA, cxA[2]));
            hA = zA * hA + (1.f - zA) * cA;
            float zB = sigmoid_(cxB[0] + gzB);
            float rB = sigmoid_(cxB[1] + grB);
            float cB = tanh_(fmaf(rB, ghB, cxB[2]));
            hB = zB * hB + (1.f - zB) * cB;
        }
    }
    if constexpr (!LAST) {
        path_state[fA * DIM + j] = hA;
        if (fB < N_FLOWS) path_state[fB * DIM + j] = hB;
    } else {
        __syncthreads();
        {  // 32 flows x 8 positions = 256 threads
            int fl = tid >> 3, t = tid & 7;
            int fg = base + fl;
            const float* s = shist[fl][t + 1];
            float h1[8];
#pragma unroll
            for (int m_ = 0; m_ < 8; ++m_) {
                float a = rob1[m_];
#pragma unroll
                for (int k = 0; k < 16; ++k) a = fmaf(s[k], roW1[k * 8 + m_], a);
                h1[m_] = selu_(a);
            }
            float h2[4];
#pragma unroll
            for (int q = 0; q < 4; ++q) {
                float a = rob2[q];
#pragma unroll
                for (int m_ = 0; m_ < 8; ++m_) a = fmaf(h1[m_], roW2[m_ * 4 + q], a);
                h2[q] = selu_(a);
            }
            float o = rob3[0];
#pragma unroll
            for (int q = 0; q < 4; ++q) o = fmaf(h2[q], roW3[q], o);
            o = softplus_(o);
            int fgc = fg < N_FLOWS ? fg : N_FLOWS - 1;
            int link = l2p[fgc * LPATH + t];
            float v = o * rcp_(link_capacity[link]);
            v += SWZ(v, 0x041F);
            v += SWZ(v, 0x081F);
            v += SWZ(v, 0x101F);
            if (t == 0 && fg < N_FLOWS) out[fg] = v;
        }
    }
}

// ---- link pass: gather-sum of sv + link GRU + fused xform ----------------
// 4 links per 256-block, one wave per link (16 j-lanes x 4 p-slices).
__global__ __launch_bounds__(256, 4) void k_link_pass(
    const int* __restrict__ p2l, const float* __restrict__ sv,
    float* __restrict__ link_state,
    const float* __restrict__ lWk_t, const float* __restrict__ lWr_t,
    const float* __restrict__ b,
    const float* __restrict__ pWk_t, const float* __restrict__ pb,
    float* __restrict__ xform) {
    __shared__ float xb_[4][16];
    __shared__ float hb_[4][16];
    int tid = threadIdx.x;
    int li = tid >> 6;
    int lane = tid & 63;
    int sl = lane >> 4, j = lane & 15;
    int link = blockIdx.x * 4 + li;
    float ps = 0.f;
#pragma unroll 4
    for (int i = 0; i < PLINK / 4; ++i) {
        int p = sl + 4 * i;
        int2 fp = ((const int2*)p2l)[link * PLINK + p];
        ps += sv[fp.y * (N_FLOWS * DIM) + fp.x * DIM + j];
    }
    ps += __shfl_xor(ps, 16, 64);
    ps += __shfl_xor(ps, 32, 64);
    float h = link_state[link * DIM + j];
    if (sl == 0) { xb_[li][j] = ps; hb_[li][j] = h; }
    float xv[16], hv[16];
#pragma unroll
    for (int q = 0; q < 4; ++q) {
        f32x4 x4 = ((const f32x4*)xb_[li])[q];
        f32x4 h4 = ((const f32x4*)hb_[li])[q];
#pragma unroll
        for (int e = 0; e < 4; ++e) { xv[q * 4 + e] = x4[e]; hv[q * 4 + e] = h4[e]; }
    }
    float az = b[j], ar = b[16 + j], ah = b[32 + j];
    float gz = b[48 + j], gr = b[64 + j], gh = b[80 + j];
    const float* kz = lWk_t + j * 48;
    const float* rz = lWr_t + j * 48;
#pragma unroll
    for (int k = 0; k < 16; ++k) {
        az = fmaf(xv[k], kz[k], az);
        ar = fmaf(xv[k], kz[16 + k], ar);
        ah = fmaf(xv[k], kz[32 + k], ah);
        gz = fmaf(hv[k], rz[k], gz);
        gr = fmaf(hv[k], rz[16 + k], gr);
        gh = fmaf(hv[k], rz[32 + k], gh);
    }
    float z = sigmoid_(az + gz);
    float r = sigmoid_(ar + gr);
    float hn = z * h + (1.f - z) * tanh_(fmaf(r, gh, ah));
    if (sl == 0) {
        link_state[link * DIM + j] = hn;
        hb_[li][j] = hn;  // re-broadcast new state for xform
    }
    float nv[16];
#pragma unroll
    for (int q = 0; q < 4; ++q) {
        f32x4 n4 = ((const f32x4*)hb_[li])[q];
#pragma unroll
        for (int e = 0; e < 4; ++e) nv[q * 4 + e] = n4[e];
    }
    int c = lane;
    if (c < 48) {
        const float* pw = pWk_t + c * 16;
        float a = pb[c];
#pragma unroll
        for (int k = 0; k < 16; ++k) a = fmaf(nv[k], pw[k], a);
        xform[link * 64 + (c & 15) * 4 + (c >> 4)] = a;
    }
}

extern "C" void kernel_launch(void* const* d_in, const int* in_sizes, int n_in,
                              void* d_out, int out_size, void* d_ws, size_t ws_size,
                              hipStream_t stream) {
    const float* flow_traffic = (const float*)d_in[0];
    const float* flow_packets = (const float*)d_in[1];
    const float* max_link_load = (const float*)d_in[2];
    const float* flow_pkts_per_burst = (const float*)d_in[3];
    const float* flow_bitrate_per_burst = (const float*)d_in[4];
    const float* flow_packet_size = (const float*)d_in[5];
    const float* flow_type = (const float*)d_in[6];
    const float* flow_ipg_mean = (const float*)d_in[7];
    const float* ibg = (const float*)d_in[8];
    const float* flow_p90 = (const float*)d_in[9];
    const float* rate = (const float*)d_in[10];
    const float* flow_ipg_var = (const float*)d_in[11];
    const float* link_capacity = (const float*)d_in[12];
    const float* fe_W1 = (const float*)d_in[13];
    const float* fe_b1 = (const float*)d_in[14];
    const float* fe_W2 = (const float*)d_in[15];
    const float* fe_b2 = (const float*)d_in[16];
    const float* le_W1 = (const float*)d_in[17];
    const float* le_b1 = (const float*)d_in[18];
    const float* le_W2 = (const float*)d_in[19];
    const float* le_b2 = (const float*)d_in[20];
    const float* att_W = (const float*)d_in[21];
    const float* att_b = (const float*)d_in[22];
    const float* pgru_Wk = (const float*)d_in[23];
    const float* pgru_Wr = (const float*)d_in[24];
    const float* pgru_b = (const float*)d_in[25];
    const float* lgru_Wk = (const float*)d_in[26];
    const float* lgru_Wr = (const float*)d_in[27];
    const float* lgru_b = (const float*)d_in[28];
    const float* ro_W1 = (const float*)d_in[29];
    const float* ro_b1 = (const float*)d_in[30];
    const float* ro_W2 = (const float*)d_in[31];
    const float* ro_b2 = (const float*)d_in[32];
    const float* ro_W3 = (const float*)d_in[33];
    const float* ro_b3 = (const float*)d_in[34];
    const int* flow_length = (const int*)d_in[35];
    const int* l2p = (const int*)d_in[36];
    const int* p2l = (const int*)d_in[37];

    float* ws = (float*)d_ws;
    float* path_state = ws;                      // 800000
    float* link_state = ws + 800000;             // 80000
    float* sv = ws + 880000;                     // 7200000  [pos][flow][16]
    float* load = ws + 8080000;                  // 5000
    float* xform = ws + 8085000;                 // 320000   [link][16][4]
    float* Wpk = ws + 8405000;                   // 768
    float* Wa_t = ws + 8405768;                  // 256
    float* lWk_t = ws + 8406024;                 // 768
    float* lWr_t = ws + 8406792;                 // 768
    float* pWk_t = ws + 8407560;                 // 768
    if (ws_size < (size_t)8408328 * 4) return;

    k_prep<<<13, 256, 0, stream>>>(pgru_Wr, att_W, lgru_Wk, lgru_Wr, pgru_Wk,
                                   Wpk, Wa_t, lWk_t, lWr_t, pWk_t);
    k_load<<<(N_LINKS * 64 + 255) / 256, 256, 0, stream>>>(p2l, flow_traffic,
                                                           link_capacity, load);
    k_flow_init<<<(N_FLOWS + 255) / 256, 256, 0, stream>>>(
        flow_traffic, flow_packets, ibg, rate, flow_p90, flow_packet_size,
        flow_bitrate_per_burst, flow_ipg_mean, flow_ipg_var, flow_pkts_per_burst,
        flow_length, flow_type, fe_W1, fe_b1, fe_W2, fe_b2, path_state);
    k_link_init<<<(N_LINKS + 255) / 256, 256, 0, stream>>>(
        link_capacity, load, max_link_load, le_W1, le_b1, le_W2, le_b2,
        pgru_Wk, pgru_b, link_state, xform);

    int fp_grid = (N_FLOWS + 31) / 32;
    for (int it = 0; it < ITERS - 1; ++it) {
        k_flow_pass<false><<<fp_grid, 256, 0, stream>>>(
            l2p, xform, path_state, sv, Wpk, pgru_b, Wa_t, att_b,
            nullptr, nullptr, nullptr, nullptr, nullptr, nullptr, nullptr,
            nullptr);
        k_link_pass<<<N_LINKS / 4, 256, 0, stream>>>(
            p2l, sv, link_state, lWk_t, lWr_t, lgru_b, pWk_t, pgru_b, xform);
    }
    // final iteration: no sv / no link update needed; fuse readout.
    k_flow_pass<true><<<fp_grid, 256, 0, stream>>>(
        l2p, xform, path_state, sv, Wpk, pgru_b, Wa_t, att_b,
        link_capacity, ro_W1, ro_b1, ro_W2, ro_b2, ro_W3, ro_b3,
        (float*)d_out);
}